// Round 13
// baseline (102.116 us; speedup 1.0000x reference)
//
#include <hip/hip_runtime.h>
#include <hip/hip_bf16.h>

#define B_ 4096
#define L_ 128
#define D_ 100
#define S_ 1024
#define R_ 512
#define KP_ 256     // pooled-K padded (200 -> 256), tail of GEMM1's K
#define K1P_ 1280   // total GEMM1 K: statement 1024 + pooled 256
#define N1_ 1024    // 2*R
#define EPS_ 1e-5f
#define NW1BLK_ (32 * (K1P_ / 32))   // 1280 W1-convert blocks

typedef short bf16x8 __attribute__((ext_vector_type(8)));
typedef short short4v __attribute__((ext_vector_type(4)));
typedef float f32x4 __attribute__((ext_vector_type(4)));

static __device__ __forceinline__ short f2bf(float x) {
  union { float f; unsigned u; } c; c.f = x;
  unsigned r = (c.u + 0x7fffu + ((c.u >> 16) & 1u)) >> 16;  // RNE
  return (short)r;
}
static __device__ __forceinline__ float bf2f(short x) {
  union { unsigned u; float f; } c; c.u = ((unsigned)(unsigned short)x) << 16;
  return c.f;
}

// ---------------- prep: W1 transpose/convert (blocks < NW1BLK_) + pool (rest) ----------
// W1t K-layout: new_k = k<200 ? 1024+k : (k<1224 ? k-200 : k)  (statement first)
__global__ __launch_bounds__(256) void prep_kernel(
    const int* __restrict__ qa_ids, const int* __restrict__ qa_lens,
    const float* __restrict__ emb, const float* __restrict__ W1,
    short* __restrict__ qas_p, short* __restrict__ W1t) {
  int t = threadIdx.x;
  if (blockIdx.x < NW1BLK_) {
    __shared__ float tile[32][33];
    int bx = blockIdx.x;
    int n0 = (bx & 31) * 32, k0 = (bx >> 5) * 32;   // bx>>5 in [0,40)
#pragma unroll
    for (int p = 0; p < 4; ++p) {
      int kk = (t >> 5) + p * 8, nn = t & 31;
      int k = k0 + kk;
      tile[kk][nn] = (k < 1224) ? W1[(size_t)k * N1_ + n0 + nn] : 0.f;
    }
    __syncthreads();
#pragma unroll
    for (int p = 0; p < 4; ++p) {
      int nn = (t >> 5) + p * 8, kk = t & 31;
      int k = k0 + kk;
      int nk = (k < 200) ? 1024 + k : (k < 1224 ? k - 200 : k);
      W1t[(size_t)(n0 + nn) * K1P_ + nk] = f2bf(tile[kk][nn]);
    }
  } else {
    int b = blockIdx.x - NW1BLK_;
    __shared__ int ids[L_ * 2];
    __shared__ __align__(16) float partial[4][2][D_];  // [wave][row-slot][d]
    int len = qa_lens[b];
    ids[t] = qa_ids[(size_t)b * (L_ * 2) + t];
    __syncthreads();
    int w = t >> 6, l = t & 63;
    int rs = l >> 5;   // wave's row-slot (0/1); row parity == rs
    int li = l & 31;   // lane within row
    if (li < 25) {     // 25 lanes x float4 = one 400B emb row; 2-deep MLP (BW-saturated)
      float4 a0 = {0.f, 0.f, 0.f, 0.f}, a1 = {0.f, 0.f, 0.f, 0.f};
      int n2 = 2 * len;
      int r = 2 * w + rs;               // residue 2w+rs (mod 8)
      for (; r + 8 < n2; r += 16) {     // 2 independent gathers in flight
        const float* row0 = emb + (size_t)ids[r] * D_;
        const float* row1 = emb + (size_t)ids[r + 8] * D_;
        float4 v0 = *reinterpret_cast<const float4*>(row0 + li * 4);
        float4 v1 = *reinterpret_cast<const float4*>(row1 + li * 4);
        a0.x += v0.x; a0.y += v0.y; a0.z += v0.z; a0.w += v0.w;
        a1.x += v1.x; a1.y += v1.y; a1.z += v1.z; a1.w += v1.w;
      }
      if (r < n2) {
        const float* row0 = emb + (size_t)ids[r] * D_;
        float4 v0 = *reinterpret_cast<const float4*>(row0 + li * 4);
        a0.x += v0.x; a0.y += v0.y; a0.z += v0.z; a0.w += v0.w;
      }
      a0.x += a1.x; a0.y += a1.y; a0.z += a1.z; a0.w += a1.w;
      *reinterpret_cast<float4*>(&partial[w][rs][li * 4]) = a0;
    }
    __syncthreads();
    short* qrow = qas_p + (size_t)b * KP_;
    if (t < 200) {
      int k = t / 100, d = t - k * 100;
      float s = partial[0][k][d] + partial[1][k][d] +
                partial[2][k][d] + partial[3][k][d];
      qrow[t] = f2bf(s / (float)(len > 0 ? len : 1));
    } else if (t < KP_) {
      qrow[t] = 0;  // zero K-pad (200..255)
    }
  }
}

// ---------------- async stage: ROWS x 64 bf16 tile -> LDS via global_load_lds ----------
template <int ROWS>
static __device__ __forceinline__ void stage_tile64(
    const short* __restrict__ gp, int stride, int k0, short* lds, int t) {
#pragma unroll
  for (int p = 0; p < ROWS / 32; ++p) {   // ROWS*8 chunks / 256 threads
    int off16 = p * 256 + t;              // 16B-chunk index within tile
    int r = off16 >> 3;
    int c = off16 & 7;
    int kc = c ^ (r & 7);
    const short* g = gp + (size_t)r * stride + k0 + kc * 8;
    __builtin_amdgcn_global_load_lds(
        (const __attribute__((address_space(1))) void*)g,
        (__attribute__((address_space(3))) void*)(lds + (size_t)off16 * 8),
        16, 0, 0);
  }
}

// ---------------- GEMM1: [4096,1280] @ W1t^T -> h1 bf16 (+b1, ReLU) + partial stats ----
// A K-layout: k in [0,1024) = sv f32 (reg-staged, converted on the fly, T14 split);
//             k in [1024,1280) = qas_p bf16 (global_load_lds). XCD-swizzled grid.
template <int NX, int NY>
__global__ __launch_bounds__(256) void gemm1_kernel(
    const float* __restrict__ sv, const short* __restrict__ qas_p,
    const short* __restrict__ W1t, const float* __restrict__ b1,
    short* __restrict__ h1, float* __restrict__ part) {
  __shared__ short As[2][128 * 64];
  __shared__ short Bs[2][64 * 64];
  __shared__ float sred[2][2][2][16];
  __shared__ float qred[2][2][2][16];
  const int t = threadIdx.x;
  const int l = t & 63, w = t >> 6;
  const int wr = w >> 1, wc = w & 1;
  constexpr int CPX = NX * NY / 8;
  const int bid = blockIdx.x;
  const int swz = (bid & 7) * CPX + (bid >> 3);
  const int bxx = swz % NX, byy = swz / NX;
  const int row0 = byy * 128, col0 = bxx * 64;
  f32x4 acc[4][2] = {};
  const int lrow = l & 15, lkc = l >> 4;
  float4 ra[4], rb[4];  // reg-staged A: 4 chunks x 8 f32
  auto loadA = [&](int k0) {
#pragma unroll
    for (int p = 0; p < 4; ++p) {
      int idx = p * 256 + t;
      int r = idx >> 3, c = idx & 7;
      const float* g = sv + (size_t)(row0 + r) * S_ + k0 + c * 8;
      ra[p] = *reinterpret_cast<const float4*>(g);
      rb[p] = *reinterpret_cast<const float4*>(g + 4);
    }
  };
  auto writeA = [&](short* dst) {
#pragma unroll
    for (int p = 0; p < 4; ++p) {
      int idx = p * 256 + t;
      int r = idx >> 3, c = idx & 7;
      int ch = c ^ (r & 7);
      bf16x8 v;
      v[0] = f2bf(ra[p].x); v[1] = f2bf(ra[p].y);
      v[2] = f2bf(ra[p].z); v[3] = f2bf(ra[p].w);
      v[4] = f2bf(rb[p].x); v[5] = f2bf(rb[p].y);
      v[6] = f2bf(rb[p].z); v[7] = f2bf(rb[p].w);
      *(bf16x8*)&dst[r * 64 + ch * 8] = v;
    }
  };
  const short* Aq = qas_p + (size_t)row0 * KP_;
  const short* Bb = W1t + (size_t)col0 * K1P_;
  auto stageB = [&](int k0, short* dst) { stage_tile64<64>(Bb, K1P_, k0, dst, t); };
  // prologue
  loadA(0);
  stageB(0, Bs[0]);
  writeA(As[0]);
  __syncthreads();
  const int nt = 20;  // 16 sv-steps + 4 qas-steps
  for (int ts = 0; ts < nt; ++ts) {
    const int cur = ts & 1;
    if (ts + 1 < nt) {
      if (ts + 1 < 16) loadA((ts + 1) * 64);                       // issue early (T14)
      else stage_tile64<128>(Aq, KP_, (ts + 1 - 16) * 64, As[cur ^ 1], t);
      stageB((ts + 1) * 64, Bs[cur ^ 1]);
    }
    bf16x8 af[2][4], bfr[2][2];
#pragma unroll
    for (int ks = 0; ks < 2; ++ks) {
#pragma unroll
      for (int m = 0; m < 4; ++m) {
        int r = wr * 64 + m * 16 + lrow;
        int ch = (ks * 4 + lkc) ^ (r & 7);
        af[ks][m] = *(const bf16x8*)&As[cur][r * 64 + ch * 8];
      }
#pragma unroll
      for (int n = 0; n < 2; ++n) {
        int r = wc * 32 + n * 16 + lrow;
        int ch = (ks * 4 + lkc) ^ (r & 7);
        bfr[ks][n] = *(const bf16x8*)&Bs[cur][r * 64 + ch * 8];
      }
    }
#pragma unroll
    for (int ks = 0; ks < 2; ++ks)
#pragma unroll
      for (int m = 0; m < 4; ++m)
#pragma unroll
        for (int n = 0; n < 2; ++n)
          acc[m][n] = __builtin_amdgcn_mfma_f32_16x16x32_bf16(
              af[ks][m], bfr[ks][n], acc[m][n], 0, 0, 0);
    if (ts + 1 < nt && ts + 1 < 16) writeA(As[cur ^ 1]);  // write late (T14)
    __syncthreads();
  }
  // epilogue: +b1, ReLU, store bf16, fused stats on STORED values
  float bvn[2];
#pragma unroll
  for (int n = 0; n < 2; ++n) bvn[n] = b1[col0 + wc * 32 + n * 16 + lrow];
  float ss[2] = {}, qq[2] = {};
#pragma unroll
  for (int m = 0; m < 4; ++m) {
#pragma unroll
    for (int n = 0; n < 2; ++n) {
      int col = col0 + wc * 32 + n * 16 + lrow;
#pragma unroll
      for (int j = 0; j < 4; ++j) {
        int row = row0 + wr * 64 + m * 16 + (l >> 4) * 4 + j;
        float v = fmaxf(acc[m][n][j] + bvn[n], 0.f);
        short vb = f2bf(v);
        h1[(size_t)row * N1_ + col] = vb;
        float f = bf2f(vb);
        ss[n] += f;
        qq[n] += f * f;
      }
    }
  }
#pragma unroll
  for (int n = 0; n < 2; ++n) {
    ss[n] += __shfl_xor(ss[n], 16);
    ss[n] += __shfl_xor(ss[n], 32);
    qq[n] += __shfl_xor(qq[n], 16);
    qq[n] += __shfl_xor(qq[n], 32);
  }
  if (l < 16) {
#pragma unroll
    for (int n = 0; n < 2; ++n) {
      sred[wr][wc][n][l] = ss[n];
      qred[wr][wc][n][l] = qq[n];
    }
  }
  __syncthreads();
  if (t < 64) {
    int c16 = t & 15, n = (t >> 4) & 1, wcc = t >> 5;
    float s = 0.f, q = 0.f;
#pragma unroll
    for (int r = 0; r < 2; ++r) { s += sred[r][wcc][n][c16]; q += qred[r][wcc][n][c16]; }
    int col = col0 + wcc * 32 + n * 16 + c16;
    part[(size_t)byy * 2 * N1_ + col] = s;
    part[(size_t)byy * 2 * N1_ + N1_ + col] = q;
  }
}

// ---------------- MFMA GEMM2 (BK=64, 2-phase async dbuf) + fused partial stats ---------
template <int BM, int BN, int WM, int WN, bool RELU, int NBIAS, int NX, int NY>
__global__ __launch_bounds__(256) void mfma_gemm(
    const short* __restrict__ A, const short* __restrict__ Bt,
    const float* __restrict__ biasp, short* __restrict__ C,
    float* __restrict__ part, int K, int N) {
  constexpr int FM = BM / WM / 16;
  constexpr int FN = BN / WN / 16;
  __shared__ short As[2][BM * 64];
  __shared__ short Bs[2][BN * 64];
  __shared__ float sred[WM][WN][FN][16];
  __shared__ float qred[WM][WN][FN][16];
  const int t = threadIdx.x;
  const int l = t & 63, w = t >> 6;
  const int wr = w / WN, wc = w % WN;
  constexpr int CPX = NX * NY / 8;
  const int bid = blockIdx.x;
  const int swz = (bid & 7) * CPX + (bid >> 3);
  const int bxx = swz % NX, byy = swz / NX;
  const int row0 = byy * BM, col0 = bxx * BN;
  const short* Ab = A + (size_t)row0 * K;
  const short* Bb = Bt + (size_t)col0 * K;
  f32x4 acc[FM][FN] = {};
  const int lrow = l & 15, lkc = l >> 4;
  const int nt = K / 64;
  stage_tile64<BM>(Ab, K, 0, As[0], t);
  stage_tile64<BN>(Bb, K, 0, Bs[0], t);
  __syncthreads();
  for (int ts = 0; ts < nt; ++ts) {
    const int cur = ts & 1;
    if (ts + 1 < nt) {
      stage_tile64<BM>(Ab, K, (ts + 1) * 64, As[cur ^ 1], t);
      stage_tile64<BN>(Bb, K, (ts + 1) * 64, Bs[cur ^ 1], t);
    }
    bf16x8 af[2][FM], bfr[2][FN];
#pragma unroll
    for (int ks = 0; ks < 2; ++ks) {
#pragma unroll
      for (int m = 0; m < FM; ++m) {
        int r = wr * (BM / WM) + m * 16 + lrow;
        int ch = (ks * 4 + lkc) ^ (r & 7);
        af[ks][m] = *(const bf16x8*)&As[cur][r * 64 + ch * 8];
      }
#pragma unroll
      for (int n = 0; n < FN; ++n) {
        int r = wc * (BN / WN) + n * 16 + lrow;
        int ch = (ks * 4 + lkc) ^ (r & 7);
        bfr[ks][n] = *(const bf16x8*)&Bs[cur][r * 64 + ch * 8];
      }
    }
#pragma unroll
    for (int ks = 0; ks < 2; ++ks)
#pragma unroll
      for (int m = 0; m < FM; ++m)
#pragma unroll
        for (int n = 0; n < FN; ++n)
          acc[m][n] = __builtin_amdgcn_mfma_f32_16x16x32_bf16(
              af[ks][m], bfr[ks][n], acc[m][n], 0, 0, 0);
    __syncthreads();
  }
  float bvn[FN];
#pragma unroll
  for (int n = 0; n < FN; ++n) {
    int col = col0 + wc * (BN / WN) + n * 16 + lrow;
    float bv = 0.f;
#pragma unroll
    for (int i = 0; i < NBIAS; ++i) bv += biasp[(size_t)i * N + col];
    bvn[n] = bv;
  }
  float ss[FN], qq[FN];
#pragma unroll
  for (int n = 0; n < FN; ++n) { ss[n] = 0.f; qq[n] = 0.f; }
#pragma unroll
  for (int m = 0; m < FM; ++m) {
#pragma unroll
    for (int n = 0; n < FN; ++n) {
      int col = col0 + wc * (BN / WN) + n * 16 + lrow;
#pragma unroll
      for (int j = 0; j < 4; ++j) {
        int row = row0 + wr * (BM / WM) + m * 16 + (l >> 4) * 4 + j;
        float v = acc[m][n][j] + bvn[n];
        if (RELU) v = fmaxf(v, 0.f);
        short vb = f2bf(v);
        C[(size_t)row * N + col] = vb;
        float f = bf2f(vb);
        ss[n] += f;
        qq[n] += f * f;
      }
    }
  }
#pragma unroll
  for (int n = 0; n < FN; ++n) {
    ss[n] += __shfl_xor(ss[n], 16);
    ss[n] += __shfl_xor(ss[n], 32);
    qq[n] += __shfl_xor(qq[n], 16);
    qq[n] += __shfl_xor(qq[n], 32);
  }
  if (l < 16) {
#pragma unroll
    for (int n = 0; n < FN; ++n) {
      sred[wr][wc][n][l] = ss[n];
      qred[wr][wc][n][l] = qq[n];
    }
  }
  __syncthreads();
  if (t < WN * FN * 16) {
    int c16 = t & 15, n = (t >> 4) % FN, wcc = t / (16 * FN);
    float s = 0.f, q = 0.f;
#pragma unroll
    for (int r = 0; r < WM; ++r) { s += sred[r][wcc][n][c16]; q += qred[r][wcc][n][c16]; }
    int col = col0 + wcc * (BN / WN) + n * 16 + c16;
    part[(size_t)byy * 2 * N + col] = s;
    part[(size_t)byy * 2 * N + N + col] = q;
  }
}

// ---------------- fold_tile: reduce stats1 + BN1-fold + transpose W2 (coalesced) -------
__global__ __launch_bounds__(256) void fold_tile(
    const float* __restrict__ part1, const float* __restrict__ W2,
    const float* __restrict__ b2, const float* __restrict__ g1,
    const float* __restrict__ beta1, short* __restrict__ W2pt,
    float* __restrict__ pbias) {
  int kt = blockIdx.x, jt = blockIdx.y;
  int t = threadIdx.x;
  int k0 = kt * 64, j0 = jt * 64;
  __shared__ float a1s[64], c1s[64];
  __shared__ float tT[64][65];     // [jj][kk] scaled, padded
  __shared__ float bred[16][64];   // [k-group][jj] bias partials
  if (t < 64) {
    float s = 0.f, q = 0.f;
    for (int b = 0; b < 32; ++b) {
      s += part1[(size_t)b * 2048 + k0 + t];
      q += part1[(size_t)b * 2048 + 1024 + k0 + t];
    }
    float mean = s * (1.f / B_);
    float var = q * (1.f / B_) - mean * mean;
    float a = g1[k0 + t] * rsqrtf(var + EPS_);
    a1s[t] = a;
    c1s[t] = beta1[k0 + t] - mean * a;
  }
  __syncthreads();
  int g = t >> 4, j4 = t & 15;
  float pb0 = 0.f, pb1 = 0.f, pb2 = 0.f, pb3 = 0.f;
#pragma unroll
  for (int p = 0; p < 4; ++p) {
    int kk = g + p * 16;
    float4 wv = *(const float4*)&W2[(size_t)(k0 + kk) * R_ + j0 + j4 * 4];
    float a = a1s[kk], cc = c1s[kk];
    tT[j4 * 4 + 0][kk] = a * wv.x;
    tT[j4 * 4 + 1][kk] = a * wv.y;
    tT[j4 * 4 + 2][kk] = a * wv.z;
    tT[j4 * 4 + 3][kk] = a * wv.w;
    pb0 += cc * wv.x; pb1 += cc * wv.y; pb2 += cc * wv.z; pb3 += cc * wv.w;
  }
  bred[g][j4 * 4 + 0] = pb0;
  bred[g][j4 * 4 + 1] = pb1;
  bred[g][j4 * 4 + 2] = pb2;
  bred[g][j4 * 4 + 3] = pb3;
  __syncthreads();
#pragma unroll
  for (int p = 0; p < 4; ++p) {
    int jj = g + p * 16;
    short4v o;
    o[0] = f2bf(tT[jj][j4 * 4 + 0]);
    o[1] = f2bf(tT[jj][j4 * 4 + 1]);
    o[2] = f2bf(tT[jj][j4 * 4 + 2]);
    o[3] = f2bf(tT[jj][j4 * 4 + 3]);
    *(short4v*)&W2pt[(size_t)(j0 + jj) * N1_ + k0 + j4 * 4] = o;
  }
  if (t < 64) {
    float pbv = 0.f;
#pragma unroll
    for (int gg = 0; gg < 16; ++gg) pbv += bred[gg][t];
    if (kt == 0) pbv += b2[j0 + t];
    pbias[(size_t)kt * R_ + j0 + t] = pbv;
  }
}

// ---------------- reduce part2 -> a2/c2 directly ---------------------------------------
__global__ __launch_bounds__(256) void reduce_bn2(
    const float* __restrict__ part2, const float* __restrict__ g2,
    const float* __restrict__ beta2, float* __restrict__ a2c2) {
  int j = blockIdx.x * 256 + threadIdx.x;
  if (j >= R_) return;
  float s = 0.f, q = 0.f;
  for (int b = 0; b < 64; ++b) {
    s += part2[(size_t)b * 1024 + j];
    q += part2[(size_t)b * 1024 + 512 + j];
  }
  float mean = s * (1.f / B_);
  float var = q * (1.f / B_) - mean * mean;
  float a = g2[j] * rsqrtf(var + EPS_);
  a2c2[j] = a;
  a2c2[R_ + j] = beta2[j] - mean * a;
}

// ---------------- final: logits = relu(a2*z2+c2) @ W3 + b3 -----------------------------
__global__ __launch_bounds__(256) void final_kernel(
    const short* __restrict__ z2, const float* __restrict__ a2c2,
    const float* __restrict__ W3, const float* __restrict__ b3,
    float* __restrict__ out) {
  int wave = threadIdx.x >> 6;
  int lane = threadIdx.x & 63;
  int row = blockIdx.x * 4 + wave;
  const short* zr = z2 + (size_t)row * R_;
  int j0 = lane * 8;
  bf16x8 zv = *(const bf16x8*)&zr[j0];
  float acc = 0.f;
#pragma unroll
  for (int i = 0; i < 8; ++i) {
    float h = fmaxf(bf2f(zv[i]) * a2c2[j0 + i] + a2c2[R_ + j0 + i], 0.f);
    acc += h * W3[j0 + i];
  }
  for (int off = 32; off > 0; off >>= 1) acc += __shfl_down(acc, off, 64);
  if (lane == 0) out[row] = acc + b3[0];
}

extern "C" void kernel_launch(void* const* d_in, const int* in_sizes, int n_in,
                              void* d_out, int out_size, void* d_ws, size_t ws_size,
                              hipStream_t stream) {
  const float* sv      = (const float*)d_in[0];
  const int*   qa_ids  = (const int*)d_in[1];
  const int*   qa_lens = (const int*)d_in[2];
  const float* emb     = (const float*)d_in[3];
  const float* W1      = (const float*)d_in[4];
  const float* b1      = (const float*)d_in[5];
  const float* g1      = (const float*)d_in[6];
  const float* beta1   = (const float*)d_in[7];
  const float* W2      = (const float*)d_in[8];
  const float* b2      = (const float*)d_in[9];
  const float* g2      = (const float*)d_in[10];
  const float* beta2   = (const float*)d_in[11];
  const float* W3      = (const float*)d_in[12];
  const float* b3      = (const float*)d_in[13];
  float* out = (float*)d_out;

  char* p = (char*)d_ws;
  short* qas_p  = (short*)p; p += (size_t)B_ * KP_ * 2;         // bf16 [4096][256]
  short* W1t    = (short*)p; p += (size_t)N1_ * K1P_ * 2;       // bf16 [1024][1280]
  short* h1     = (short*)p; p += (size_t)B_ * N1_ * 2;         // bf16 [4096][1024]
  short* W2pt   = (short*)p; p += (size_t)R_ * N1_ * 2;         // bf16 [512][1024]
  short* z2     = (short*)p; p += (size_t)B_ * R_ * 2;          // bf16 [4096][512]
  float* pbias  = (float*)p; p += (size_t)16 * R_ * 4;          // [16][512]
  float* a2c2   = (float*)p; p += 2 * R_ * 4;
  float* part1  = (float*)p; p += (size_t)32 * 2 * N1_ * 4;     // [32 row-tiles][2048]
  float* part2  = (float*)p;                                    // [64 row-tiles][1024]

  // prep: blocks [0,1280) = W1 transpose/convert; rest = pool (no sv copy)
  prep_kernel<<<NW1BLK_ + B_, 256, 0, stream>>>(qa_ids, qa_lens, emb, W1, qas_p, W1t);
  // GEMM1: A = [sv f32 (reg-staged) | qas_p bf16 (async)] @ W1t^T; XCD-swizzled
  gemm1_kernel<16, 32><<<512, 256, 0, stream>>>(sv, qas_p, W1t, b1, h1, part1);
  // fold: stats1 reduce + BN1-fold into W2 (transposed bf16) + bias partials
  fold_tile<<<dim3(16, 8), 256, 0, stream>>>(part1, W2, b2, g1, beta1, W2pt, pbias);
  // GEMM2: h1 @ W2pt^T -> z2 bf16, bias = sum(pbias); XCD-swizzled
  mfma_gemm<64, 64, 2, 2, false, 16, 8, 64>
      <<<512, 256, 0, stream>>>(h1, W2pt, pbias, z2, part2, N1_, R_);
  reduce_bn2<<<2, 256, 0, stream>>>(part2, g2, beta2, a2c2);
  final_kernel<<<B_ / 4, 256, 0, stream>>>(z2, a2c2, W3, b3, out);
}

// Round 14
// 97.785 us; speedup vs baseline: 1.0443x; 1.0443x over previous
//
#include <hip/hip_runtime.h>
#include <hip/hip_bf16.h>

#define B_ 4096
#define L_ 128
#define D_ 100
#define S_ 1024
#define R_ 512
#define K1P_ 1280   // 2*D + S padded to multiple of 64
#define N1_ 1024    // 2*R
#define EPS_ 1e-5f
#define NW1BLK_ (32 * (K1P_ / 32))   // 1280 W1-convert blocks

typedef short bf16x8 __attribute__((ext_vector_type(8)));
typedef short short4v __attribute__((ext_vector_type(4)));
typedef float f32x4 __attribute__((ext_vector_type(4)));

static __device__ __forceinline__ short f2bf(float x) {
  union { float f; unsigned u; } c; c.f = x;
  unsigned r = (c.u + 0x7fffu + ((c.u >> 16) & 1u)) >> 16;  // RNE
  return (short)r;
}
static __device__ __forceinline__ float bf2f(short x) {
  union { unsigned u; float f; } c; c.u = ((unsigned)(unsigned short)x) << 16;
  return c.f;
}

// ---------------- prep: W1 transpose/convert (blocks < NW1BLK_) + pool (rest) ----------
__global__ __launch_bounds__(256) void prep_kernel(
    const float* __restrict__ sv, const int* __restrict__ qa_ids,
    const int* __restrict__ qa_lens, const float* __restrict__ emb,
    const float* __restrict__ W1, short* __restrict__ qas,
    short* __restrict__ W1t) {
  int t = threadIdx.x;
  if (blockIdx.x < NW1BLK_) {
    // W1 [1224][1024] f32 -> W1t [1024][1280] bf16 (transposed, zero-padded)
    __shared__ float tile[32][33];
    int bx = blockIdx.x;
    int n0 = (bx & 31) * 32, k0 = (bx >> 5) * 32;   // bx>>5 in [0,40)
#pragma unroll
    for (int p = 0; p < 4; ++p) {
      int kk = (t >> 5) + p * 8, nn = t & 31;
      int k = k0 + kk;
      tile[kk][nn] = (k < 1224) ? W1[(size_t)k * N1_ + n0 + nn] : 0.f;
    }
    __syncthreads();
#pragma unroll
    for (int p = 0; p < 4; ++p) {
      int nn = (t >> 5) + p * 8, kk = t & 31;
      W1t[(size_t)(n0 + nn) * K1P_ + k0 + kk] = f2bf(tile[kk][nn]);
    }
  } else {
    int b = blockIdx.x - NW1BLK_;
    __shared__ int ids[L_ * 2];
    __shared__ __align__(16) float partial[4][2][D_];  // [wave][row-slot][d]
    int len = qa_lens[b];
    ids[t] = qa_ids[(size_t)b * (L_ * 2) + t];
    __syncthreads();
    int w = t >> 6, l = t & 63;
    int rs = l >> 5;   // wave's row-slot (0/1); row parity == rs
    int li = l & 31;   // lane within row
    if (li < 25) {     // 25 lanes x float4 = one 400B emb row; 2-deep MLP (BW-saturated)
      float4 a0 = {0.f, 0.f, 0.f, 0.f}, a1 = {0.f, 0.f, 0.f, 0.f};
      int n2 = 2 * len;
      int r = 2 * w + rs;               // residue 2w+rs (mod 8)
      for (; r + 8 < n2; r += 16) {     // 2 independent gathers in flight
        const float* row0 = emb + (size_t)ids[r] * D_;
        const float* row1 = emb + (size_t)ids[r + 8] * D_;
        float4 v0 = *reinterpret_cast<const float4*>(row0 + li * 4);
        float4 v1 = *reinterpret_cast<const float4*>(row1 + li * 4);
        a0.x += v0.x; a0.y += v0.y; a0.z += v0.z; a0.w += v0.w;
        a1.x += v1.x; a1.y += v1.y; a1.z += v1.z; a1.w += v1.w;
      }
      if (r < n2) {
        const float* row0 = emb + (size_t)ids[r] * D_;
        float4 v0 = *reinterpret_cast<const float4*>(row0 + li * 4);
        a0.x += v0.x; a0.y += v0.y; a0.z += v0.z; a0.w += v0.w;
      }
      a0.x += a1.x; a0.y += a1.y; a0.z += a1.z; a0.w += a1.w;
      *reinterpret_cast<float4*>(&partial[w][rs][li * 4]) = a0;
    }
    __syncthreads();
    short* qrow = qas + (size_t)b * K1P_;
    if (t < 200) {
      int k = t / 100, d = t - k * 100;
      float s = partial[0][k][d] + partial[1][k][d] +
                partial[2][k][d] + partial[3][k][d];
      qrow[t] = f2bf(s / (float)(len > 0 ? len : 1));
    }
    {  // statement copy: 256 threads x float4 -> 4x bf16
      float4 v = *reinterpret_cast<const float4*>(sv + (size_t)b * S_ + t * 4);
      short4v o;
      o[0] = f2bf(v.x); o[1] = f2bf(v.y); o[2] = f2bf(v.z); o[3] = f2bf(v.w);
      *(short4v*)&qrow[200 + t * 4] = o;
    }
    if (t < K1P_ - 1224) qrow[1224 + t] = 0;  // zero K-pad (1224..1279)
  }
}

// ---------------- async stage: ROWS x 64 bf16 tile -> LDS via global_load_lds ----------
// LDS linear (HW: wave base + lane*16). Swizzle (involution, 3-bit XOR) applied to the
// GLOBAL source chunk so LDS slot c of row r holds global chunk c ^ (r&7).
template <int ROWS>
static __device__ __forceinline__ void stage_tile64(
    const short* __restrict__ gp, int stride, int k0, short* lds, int t) {
#pragma unroll
  for (int p = 0; p < ROWS / 32; ++p) {   // ROWS*8 chunks / 256 threads
    int off16 = p * 256 + t;              // 16B-chunk index within tile
    int r = off16 >> 3;
    int c = off16 & 7;
    int kc = c ^ (r & 7);
    const short* g = gp + (size_t)r * stride + k0 + kc * 8;
    __builtin_amdgcn_global_load_lds(
        (const __attribute__((address_space(1))) void*)g,
        (__attribute__((address_space(3))) void*)(lds + (size_t)off16 * 8),
        16, 0, 0);
  }
}

// ---------------- MFMA GEMM (BK=64, 2-phase async dbuf) + fused column partial-stats ---
// 1D grid of NX*NY blocks, XCD-swizzled (T1): consecutive logical tiles share an XCD's
// L2 so the A row-panel staged by NX col-tiles is fetched once per XCD, not 8x.
// bias[col] = sum_{i<NBIAS} biasp[i*N + col]
template <int BM, int BN, int WM, int WN, bool RELU, int NBIAS, int NX, int NY>
__global__ __launch_bounds__(256) void mfma_gemm(
    const short* __restrict__ A, const short* __restrict__ Bt,
    const float* __restrict__ biasp, short* __restrict__ C,
    float* __restrict__ part, int K, int N) {
  constexpr int FM = BM / WM / 16;
  constexpr int FN = BN / WN / 16;
  __shared__ short As[2][BM * 64];
  __shared__ short Bs[2][BN * 64];
  __shared__ float sred[WM][WN][FN][16];
  __shared__ float qred[WM][WN][FN][16];
  const int t = threadIdx.x;
  const int l = t & 63, w = t >> 6;
  const int wr = w / WN, wc = w % WN;
  // XCD-aware bijective remap (NX*NY % 8 == 0): physical bid -> logical tile
  constexpr int CPX = NX * NY / 8;
  const int bid = blockIdx.x;
  const int swz = (bid & 7) * CPX + (bid >> 3);
  const int bxx = swz % NX, byy = swz / NX;
  const int row0 = byy * BM, col0 = bxx * BN;
  const short* Ab = A + (size_t)row0 * K;
  const short* Bb = Bt + (size_t)col0 * K;
  f32x4 acc[FM][FN] = {};
  const int lrow = l & 15, lkc = l >> 4;
  const int nt = K / 64;
  stage_tile64<BM>(Ab, K, 0, As[0], t);
  stage_tile64<BN>(Bb, K, 0, Bs[0], t);
  __syncthreads();  // vmcnt(0)+lgkm drain + barrier
  for (int ts = 0; ts < nt; ++ts) {
    const int cur = ts & 1;
    if (ts + 1 < nt) {  // prefetch next K-tile into the other buffer
      stage_tile64<BM>(Ab, K, (ts + 1) * 64, As[cur ^ 1], t);
      stage_tile64<BN>(Bb, K, (ts + 1) * 64, Bs[cur ^ 1], t);
    }
    bf16x8 af[2][FM], bfr[2][FN];
#pragma unroll
    for (int ks = 0; ks < 2; ++ks) {
#pragma unroll
      for (int m = 0; m < FM; ++m) {
        int r = wr * (BM / WM) + m * 16 + lrow;
        int ch = (ks * 4 + lkc) ^ (r & 7);
        af[ks][m] = *(const bf16x8*)&As[cur][r * 64 + ch * 8];
      }
#pragma unroll
      for (int n = 0; n < FN; ++n) {
        int r = wc * (BN / WN) + n * 16 + lrow;
        int ch = (ks * 4 + lkc) ^ (r & 7);
        bfr[ks][n] = *(const bf16x8*)&Bs[cur][r * 64 + ch * 8];
      }
    }
#pragma unroll
    for (int ks = 0; ks < 2; ++ks)
#pragma unroll
      for (int m = 0; m < FM; ++m)
#pragma unroll
        for (int n = 0; n < FN; ++n)
          acc[m][n] = __builtin_amdgcn_mfma_f32_16x16x32_bf16(
              af[ks][m], bfr[ks][n], acc[m][n], 0, 0, 0);
    __syncthreads();  // drains prefetch + protects buffer reuse
  }
  // epilogue: C/D layout col = lane&15, row = (lane>>4)*4 + j; fused stats on STORED vals
  float bvn[FN];
#pragma unroll
  for (int n = 0; n < FN; ++n) {  // bias hoisted out of the m loop
    int col = col0 + wc * (BN / WN) + n * 16 + lrow;
    float bv = 0.f;
#pragma unroll
    for (int i = 0; i < NBIAS; ++i) bv += biasp[(size_t)i * N + col];
    bvn[n] = bv;
  }
  float ss[FN], qq[FN];
#pragma unroll
  for (int n = 0; n < FN; ++n) { ss[n] = 0.f; qq[n] = 0.f; }
#pragma unroll
  for (int m = 0; m < FM; ++m) {
#pragma unroll
    for (int n = 0; n < FN; ++n) {
      int col = col0 + wc * (BN / WN) + n * 16 + lrow;
#pragma unroll
      for (int j = 0; j < 4; ++j) {
        int row = row0 + wr * (BM / WM) + m * 16 + (l >> 4) * 4 + j;
        float v = acc[m][n][j] + bvn[n];
        if (RELU) v = fmaxf(v, 0.f);
        short vb = f2bf(v);
        C[(size_t)row * N + col] = vb;
        float f = bf2f(vb);
        ss[n] += f;
        qq[n] += f * f;
      }
    }
  }
#pragma unroll
  for (int n = 0; n < FN; ++n) {
    ss[n] += __shfl_xor(ss[n], 16);
    ss[n] += __shfl_xor(ss[n], 32);
    qq[n] += __shfl_xor(qq[n], 16);
    qq[n] += __shfl_xor(qq[n], 32);
  }
  if (l < 16) {
#pragma unroll
    for (int n = 0; n < FN; ++n) {
      sred[wr][wc][n][l] = ss[n];
      qred[wr][wc][n][l] = qq[n];
    }
  }
  __syncthreads();
  if (t < WN * FN * 16) {
    int c16 = t & 15, n = (t >> 4) % FN, wcc = t / (16 * FN);
    float s = 0.f, q = 0.f;
#pragma unroll
    for (int r = 0; r < WM; ++r) { s += sred[r][wcc][n][c16]; q += qred[r][wcc][n][c16]; }
    int col = col0 + wcc * (BN / WN) + n * 16 + c16;
    part[(size_t)byy * 2 * N + col] = s;
    part[(size_t)byy * 2 * N + N + col] = q;
  }
}

// ---------------- fold_tile: reduce stats1 + BN1-fold + transpose W2 (coalesced) -------
// grid (16 kt, 8 jt). Writes W2pt[j][k] = a1[k]*W2[k][j] (bf16) and
// pbias[kt][j] = sum_{k in tile} c1[k]*W2[k][j]  (+ b2[j] folded into kt==0).
__global__ __launch_bounds__(256) void fold_tile(
    const float* __restrict__ part1, const float* __restrict__ W2,
    const float* __restrict__ b2, const float* __restrict__ g1,
    const float* __restrict__ beta1, short* __restrict__ W2pt,
    float* __restrict__ pbias) {
  int kt = blockIdx.x, jt = blockIdx.y;
  int t = threadIdx.x;
  int k0 = kt * 64, j0 = jt * 64;
  __shared__ float a1s[64], c1s[64];
  __shared__ float tT[64][65];     // [jj][kk] scaled, padded
  __shared__ float bred[16][64];   // [k-group][jj] bias partials
  if (t < 64) {  // phase A: reduce part1 over 32 row-tiles -> a1,c1 for this k-slice
    float s = 0.f, q = 0.f;
    for (int b = 0; b < 32; ++b) {
      s += part1[(size_t)b * 2048 + k0 + t];
      q += part1[(size_t)b * 2048 + 1024 + k0 + t];
    }
    float mean = s * (1.f / B_);
    float var = q * (1.f / B_) - mean * mean;
    float a = g1[k0 + t] * rsqrtf(var + EPS_);
    a1s[t] = a;
    c1s[t] = beta1[k0 + t] - mean * a;
  }
  __syncthreads();
  int g = t >> 4, j4 = t & 15;  // g: k-group 0..15, j4: j-quad 0..15
  float pb0 = 0.f, pb1 = 0.f, pb2 = 0.f, pb3 = 0.f;
#pragma unroll
  for (int p = 0; p < 4; ++p) {  // phase B: coalesced W2 rows -> scaled transpose in LDS
    int kk = g + p * 16;
    float4 wv = *(const float4*)&W2[(size_t)(k0 + kk) * R_ + j0 + j4 * 4];
    float a = a1s[kk], cc = c1s[kk];
    tT[j4 * 4 + 0][kk] = a * wv.x;
    tT[j4 * 4 + 1][kk] = a * wv.y;
    tT[j4 * 4 + 2][kk] = a * wv.z;
    tT[j4 * 4 + 3][kk] = a * wv.w;
    pb0 += cc * wv.x; pb1 += cc * wv.y; pb2 += cc * wv.z; pb3 += cc * wv.w;
  }
  bred[g][j4 * 4 + 0] = pb0;
  bred[g][j4 * 4 + 1] = pb1;
  bred[g][j4 * 4 + 2] = pb2;
  bred[g][j4 * 4 + 3] = pb3;
  __syncthreads();
#pragma unroll
  for (int p = 0; p < 4; ++p) {  // write W2pt rows (coalesced in k)
    int jj = g + p * 16;
    short4v o;
    o[0] = f2bf(tT[jj][j4 * 4 + 0]);
    o[1] = f2bf(tT[jj][j4 * 4 + 1]);
    o[2] = f2bf(tT[jj][j4 * 4 + 2]);
    o[3] = f2bf(tT[jj][j4 * 4 + 3]);
    *(short4v*)&W2pt[(size_t)(j0 + jj) * N1_ + k0 + j4 * 4] = o;
  }
  if (t < 64) {
    float pbv = 0.f;
#pragma unroll
    for (int gg = 0; gg < 16; ++gg) pbv += bred[gg][t];
    if (kt == 0) pbv += b2[j0 + t];
    pbias[(size_t)kt * R_ + j0 + t] = pbv;
  }
}

// ---------------- reduce part2 -> a2/c2 directly ---------------------------------------
__global__ __launch_bounds__(256) void reduce_bn2(
    const float* __restrict__ part2, const float* __restrict__ g2,
    const float* __restrict__ beta2, float* __restrict__ a2c2) {
  int j = blockIdx.x * 256 + threadIdx.x;
  if (j >= R_) return;
  float s = 0.f, q = 0.f;
  for (int b = 0; b < 64; ++b) {
    s += part2[(size_t)b * 1024 + j];
    q += part2[(size_t)b * 1024 + 512 + j];
  }
  float mean = s * (1.f / B_);
  float var = q * (1.f / B_) - mean * mean;
  float a = g2[j] * rsqrtf(var + EPS_);
  a2c2[j] = a;
  a2c2[R_ + j] = beta2[j] - mean * a;
}

// ---------------- final: logits = relu(a2*z2+c2) @ W3 + b3 -----------------------------
__global__ __launch_bounds__(256) void final_kernel(
    const short* __restrict__ z2, const float* __restrict__ a2c2,
    const float* __restrict__ W3, const float* __restrict__ b3,
    float* __restrict__ out) {
  int wave = threadIdx.x >> 6;
  int lane = threadIdx.x & 63;
  int row = blockIdx.x * 4 + wave;
  const short* zr = z2 + (size_t)row * R_;
  int j0 = lane * 8;
  bf16x8 zv = *(const bf16x8*)&zr[j0];
  float acc = 0.f;
#pragma unroll
  for (int i = 0; i < 8; ++i) {
    float h = fmaxf(bf2f(zv[i]) * a2c2[j0 + i] + a2c2[R_ + j0 + i], 0.f);
    acc += h * W3[j0 + i];
  }
  for (int off = 32; off > 0; off >>= 1) acc += __shfl_down(acc, off, 64);
  if (lane == 0) out[row] = acc + b3[0];
}

extern "C" void kernel_launch(void* const* d_in, const int* in_sizes, int n_in,
                              void* d_out, int out_size, void* d_ws, size_t ws_size,
                              hipStream_t stream) {
  const float* sv      = (const float*)d_in[0];
  const int*   qa_ids  = (const int*)d_in[1];
  const int*   qa_lens = (const int*)d_in[2];
  const float* emb     = (const float*)d_in[3];
  const float* W1      = (const float*)d_in[4];
  const float* b1      = (const float*)d_in[5];
  const float* g1      = (const float*)d_in[6];
  const float* beta1   = (const float*)d_in[7];
  const float* W2      = (const float*)d_in[8];
  const float* b2      = (const float*)d_in[9];
  const float* g2      = (const float*)d_in[10];
  const float* beta2   = (const float*)d_in[11];
  const float* W3      = (const float*)d_in[12];
  const float* b3      = (const float*)d_in[13];
  float* out = (float*)d_out;

  char* p = (char*)d_ws;
  short* qas    = (short*)p; p += (size_t)B_ * K1P_ * 2;        // bf16 [4096][1280]
  short* W1t    = (short*)p; p += (size_t)N1_ * K1P_ * 2;       // bf16 [1024][1280]
  short* h1     = (short*)p; p += (size_t)B_ * N1_ * 2;         // bf16 [4096][1024]
  short* W2pt   = (short*)p; p += (size_t)R_ * N1_ * 2;         // bf16 [512][1024]
  short* z2     = (short*)p; p += (size_t)B_ * R_ * 2;          // bf16 [4096][512]
  float* pbias  = (float*)p; p += (size_t)16 * R_ * 4;          // [16][512]
  float* a2c2   = (float*)p; p += 2 * R_ * 4;
  float* part1  = (float*)p; p += (size_t)32 * 2 * N1_ * 4;     // [32 row-tiles][2048]
  float* part2  = (float*)p;                                    // [64 row-tiles][1024]

  // prep: blocks [0,1280) = W1 transpose/convert (run first); rest = pool+concat
  prep_kernel<<<NW1BLK_ + B_, 256, 0, stream>>>(
      sv, qa_ids, qa_lens, emb, W1, qas, W1t);
  // GEMM1: [4096,1280] @ [1280,1024] -> h1 bf16, +b1, ReLU; XCD-swizzled 512-block grid
  mfma_gemm<128, 64, 2, 2, true, 1, 16, 32>
      <<<512, 256, 0, stream>>>(qas, W1t, b1, h1, part1, K1P_, N1_);
  // fold: stats1 reduce + BN1-fold into W2 (transposed bf16) + bias partials
  fold_tile<<<dim3(16, 8), 256, 0, stream>>>(part1, W2, b2, g1, beta1, W2pt, pbias);
  // GEMM2: [4096,1024] @ [1024,512] -> z2 bf16, bias = sum(pbias); XCD-swizzled
  mfma_gemm<64, 64, 2, 2, false, 16, 8, 64>
      <<<512, 256, 0, stream>>>(h1, W2pt, pbias, z2, part2, N1_, R_);
  reduce_bn2<<<2, 256, 0, stream>>>(part2, g2, beta2, a2c2);
  final_kernel<<<B_ / 4, 256, 0, stream>>>(z2, a2c2, W3, b3, out);
}